// Round 3
// baseline (336.446 us; speedup 1.0000x reference)
//
#include <hip/hip_runtime.h>

#define BATCH     131072
#define DIM       256
#define NBLOCKS   4096
#define TPB       256
#define WPB       (TPB / 64)            // waves per block = 4
#define TOTWAVES  (NBLOCKS * WPB)       // 16384 waves
#define STRIDE2   (2 * TOTWAVES)        // row stride per unrolled iteration
#define NITER     (BATCH / STRIDE2)     // 4 iterations, 8 rows per wave

typedef float fvec4 __attribute__((ext_vector_type(4)));  // native vec for nontemporal builtin

// SALU broadcast from a fixed lane — no LDS pipe, no lgkmcnt.
__device__ __forceinline__ float bcast(float v, int lane_const) {
    return __int_as_float(__builtin_amdgcn_readlane(__float_as_int(v), lane_const));
}

__device__ __forceinline__ void nt_store4(float* p, const float4& v) {
    fvec4 nv; nv.x = v.x; nv.y = v.y; nv.z = v.z; nv.w = v.w;
    __builtin_nontemporal_store(nv, (fvec4*)p);
}

// One wave owns one row: lane i holds cols [4i,4i+3] as float4.
__global__ __launch_bounds__(TPB) void rotor_main(
    const float* __restrict__ A,      // state_a [BATCH][DIM]
    const float* __restrict__ Bst,    // state_b [BATCH][DIM]
    const float* __restrict__ theta,  // [6]
    float* __restrict__ out,          // transformed [BATCH][DIM]
    float* __restrict__ partials)     // [NBLOCKS] squared-diff partial sums
{
    const float t0 = theta[0], t1 = theta[1], t2 = theta[2];
    const float t3 = theta[3], t4 = theta[4], t5 = theta[5];
    const float a2 = t0*t0 + t1*t1 + t2*t2 + t3*t3 + t4*t4 + t5*t5;
    float alpha, beta, gamma;
    if (a2 < 1e-30f) {
        alpha = 0.5f; beta = 0.0f; gamma = -0.125f;
    } else {
        const float a = sqrtf(a2);
        alpha = sinf(0.5f * a) / a;         // sin(t)/a
        beta  = cosf(0.5f * a) - 1.0f;      // cos(t)-1
        gamma = beta / a2;                  // (cos(t)-1)/a^2
    }

    const int lane = threadIdx.x & 63;
    const int wid  = threadIdx.x >> 6;
    const int gw   = blockIdx.x * WPB + wid;

    float acc = 0.0f;
    #pragma unroll
    for (int it = 0; it < NITER; ++it) {
        const int r0 = gw + it * STRIDE2;
        const int r1 = r0 + TOTWAVES;
        const size_t base0 = (size_t)r0 * DIM;
        const size_t base1 = (size_t)r1 * DIM;

        // 4 independent 1 KB wave-loads in flight before any consumption
        const float4 a0 = ((const float4*)(A   + base0))[lane];
        const float4 a1 = ((const float4*)(A   + base1))[lane];
        const float4 b0 = ((const float4*)(Bst + base0))[lane];
        const float4 b1 = ((const float4*)(Bst + base1))[lane];

        // sparse dot s = theta . x[1..6]; computed branch-free in all lanes,
        // only lanes 0/1 hold valid operands and only those are read back.
        const float pA0 = t0*a0.y + t1*a0.z + t2*a0.w;   // valid in lane 0
        const float pB0 = t3*a0.x + t4*a0.y + t5*a0.z;   // valid in lane 1
        const float sv0 = bcast(pA0, 0) + bcast(pB0, 1);
        const float x00 = bcast(a0.x, 0);
        const float w0  = gamma * sv0 - alpha * x00;

        const float pA1 = t0*a1.y + t1*a1.z + t2*a1.w;
        const float pB1 = t3*a1.x + t4*a1.y + t5*a1.z;
        const float sv1 = bcast(pA1, 0) + bcast(pB1, 1);
        const float x01 = bcast(a1.x, 0);
        const float w1  = gamma * sv1 - alpha * x01;

        float4 o0 = a0, o1 = a1;
        if (lane == 0) {
            o0.x = x00 + beta * x00 + alpha * sv0;
            o0.y += t0 * w0; o0.z += t1 * w0; o0.w += t2 * w0;
            o1.x = x01 + beta * x01 + alpha * sv1;
            o1.y += t0 * w1; o1.z += t1 * w1; o1.w += t2 * w1;
        } else if (lane == 1) {
            o0.x += t3 * w0; o0.y += t4 * w0; o0.z += t5 * w0;
            o1.x += t3 * w1; o1.y += t4 * w1; o1.z += t5 * w1;
        }

        // nontemporal: don't let the write stream evict L3-resident inputs
        nt_store4(out + base0 + 4 * (size_t)lane, o0);
        nt_store4(out + base1 + 4 * (size_t)lane, o1);

        float dx = o0.x - b0.x, dy = o0.y - b0.y, dz = o0.z - b0.z, dw = o0.w - b0.w;
        acc += dx*dx + dy*dy + dz*dz + dw*dw;
        dx = o1.x - b1.x; dy = o1.y - b1.y; dz = o1.z - b1.z; dw = o1.w - b1.w;
        acc += dx*dx + dy*dy + dz*dz + dw*dw;
    }

    // wave reduce -> block reduce -> one partial per block (no atomics)
    #pragma unroll
    for (int off = 32; off > 0; off >>= 1) acc += __shfl_xor(acc, off, 64);
    __shared__ float smem[WPB];
    if (lane == 0) smem[wid] = acc;
    __syncthreads();
    if (threadIdx.x == 0) {
        float s = 0.0f;
        #pragma unroll
        for (int i = 0; i < WPB; ++i) s += smem[i];
        partials[blockIdx.x] = s;
    }
}

// Final reduction WRITES the loss slot (d_out is poisoned 0xAA, never accumulate into it).
__global__ __launch_bounds__(256) void rotor_loss(
    const float* __restrict__ partials, float* __restrict__ loss)
{
    const int tid = threadIdx.x;
    double acc = 0.0;
    for (int i = tid; i < NBLOCKS; i += 256) acc += (double)partials[i];
    #pragma unroll
    for (int off = 32; off > 0; off >>= 1) acc += __shfl_xor(acc, off, 64);
    __shared__ double smem[4];
    const int lane = tid & 63, wid = tid >> 6;
    if (lane == 0) smem[wid] = acc;
    __syncthreads();
    if (tid == 0) {
        const double s = smem[0] + smem[1] + smem[2] + smem[3];
        *loss = (float)(s / (double)((size_t)BATCH * (size_t)DIM));
    }
}

extern "C" void kernel_launch(void* const* d_in, const int* in_sizes, int n_in,
                              void* d_out, int out_size, void* d_ws, size_t ws_size,
                              hipStream_t stream) {
    const float* A     = (const float*)d_in[0];   // state_a
    const float* Bst   = (const float*)d_in[1];   // state_b
    const float* theta = (const float*)d_in[2];   // bivector_coeffs

    float* out      = (float*)d_out;
    float* loss     = out + (size_t)BATCH * (size_t)DIM;
    float* partials = (float*)d_ws;               // NBLOCKS floats

    rotor_main<<<NBLOCKS, TPB, 0, stream>>>(A, Bst, theta, out, partials);
    rotor_loss<<<1, 256, 0, stream>>>(partials, loss);
}